// Round 1
// baseline (1443.618 us; speedup 1.0000x reference)
//
#include <hip/hip_runtime.h>
#include <cstdint>

typedef unsigned short u16;
typedef unsigned int u32;
typedef __attribute__((ext_vector_type(8))) short bf16x8;   // 8 bf16 (4 VGPRs)
typedef __attribute__((ext_vector_type(4))) float f32x4;

namespace {
constexpr int R_   = 6;
constexpr int H_   = 512;
constexpr int N_   = 196;
constexpr int V_   = 2001;
constexpr int BR_  = 768;
constexpr int MBIG = BR_ * N_;     // 150528
constexpr int VP   = 2016;         // padded vocab stride (16-elem aligned)

// workspace layout (float offsets)
constexpr size_t OFF_QEMB  = 0;
constexpr size_t OFF_QREPR = OFF_QEMB  + (size_t)BR_ * H_;
constexpr size_t OFF_QPROJ = OFF_QREPR + (size_t)BR_ * H_;  // q_emb@Wa_bot + ba
constexpr size_t OFF_JOINT = OFF_QPROJ + (size_t)BR_ * H_;
constexpr size_t OFF_LPROJ = OFF_JOINT + (size_t)BR_ * H_;  // joint@Wa_top
constexpr size_t OFF_VEMB  = OFF_LPROJ + (size_t)BR_ * H_;
constexpr size_t OFF_P0    = OFF_VEMB  + (size_t)BR_ * H_;
constexpr size_t OFF_HID   = OFF_P0    + (size_t)BR_ * H_;  // 768x1024
constexpr size_t OFF_S0    = OFF_HID   + (size_t)BR_ * 2 * H_;
constexpr size_t OFF_Z0    = OFF_S0    + (size_t)MBIG;
constexpr size_t OFF_WC2P  = OFF_Z0    + 1024;
constexpr size_t OFF_WAT   = OFF_WC2P  + (size_t)1024 * VP; // 512x512 bf16 (as u16)
}

__device__ __forceinline__ u16 f2bf(float f) {
    u32 x = __float_as_uint(f);
    return (u16)((x + 0x7fffu + ((x >> 16) & 1u)) >> 16);   // RNE
}

// ---------------- init / prep ----------------

__global__ __launch_bounds__(256) void k_zero(float* __restrict__ s0,
                                              float* __restrict__ joint) {
    int idx = blockIdx.x * 256 + threadIdx.x;        // grid exactly covers both
    if (idx < MBIG) s0[idx] = 0.f;
    else            joint[idx - MBIG] = 0.f;
}

__global__ __launch_bounds__(256) void k_castWaT(const float* __restrict__ Wa,
                                                 u16* __restrict__ WaT) {
    int idx = blockIdx.x * 256 + threadIdx.x;        // 512*512
    int n = idx >> 9, k = idx & 511;
    WaT[idx] = f2bf(Wa[(size_t)k * 512 + n]);        // WaT[n][k] = Wa_top[k][n]
}

__global__ __launch_bounds__(256) void k_padWc2(const float* __restrict__ Wc2,
                                                float* __restrict__ Wc2p) {
    int idx = blockIdx.x * 256 + threadIdx.x;        // 1024*2016
    int k = idx / VP, j = idx - k * VP;
    Wc2p[idx] = (j < V_) ? Wc2[(size_t)k * V_ + j] : 0.f;
}

__global__ __launch_bounds__(256) void k_copy4(const float4* __restrict__ src,
                                               float4* __restrict__ dst) {
    int i = blockIdx.x * 256 + threadIdx.x;
    dst[i] = src[i];
}

// ---------------- generic f32 row-block GEMM ----------------
// out[i][col] = act( sum_k x[i][k]*W[k][col] + bias[col] )
// block: 8 rows x 512 cols, 256 threads (thread = 4 cols, 4 rows; 2 row-halves)
// MODE 0: store to out (guard col<Hout). MODE 1: joint += q_repr * val.
template <int K, bool RELU, bool BIAS, int MODE>
__global__ __launch_bounds__(256) void k_rowgemm(
    const float* __restrict__ x, const float* __restrict__ W, int ldW,
    const float* __restrict__ bias, float* __restrict__ out, int ldOut, int Hout,
    const float* __restrict__ qrepr, float* __restrict__ joint) {
    __shared__ float xs[8][K];
    const int i0 = blockIdx.x * 8;
    const int t = threadIdx.x;
    for (int idx = t; idx < 8 * K; idx += 256) {
        int r = idx / K, k = idx - r * K;
        xs[r][k] = x[(size_t)(i0 + r) * K + k];
    }
    __syncthreads();
    const int col = blockIdx.y * 512 + (t & 127) * 4;
    const int rh = (t >> 7) * 4;
    if (col < ldW) {
        float acc[4][4] = {};
#pragma unroll 4
        for (int k = 0; k < K; ++k) {
            const float4 w4 = *(const float4*)&W[(size_t)k * ldW + col];
#pragma unroll
            for (int r = 0; r < 4; ++r) {
                const float xv = xs[rh + r][k];
                acc[r][0] += xv * w4.x; acc[r][1] += xv * w4.y;
                acc[r][2] += xv * w4.z; acc[r][3] += xv * w4.w;
            }
        }
#pragma unroll
        for (int r = 0; r < 4; ++r) {
            const int i = i0 + rh + r;
            if constexpr (MODE == 0) {
#pragma unroll
                for (int c = 0; c < 4; ++c) {
                    if (col + c < Hout) {
                        float v = acc[r][c];
                        if constexpr (BIAS) v += bias[col + c];
                        if constexpr (RELU) v = fmaxf(v, 0.f);
                        out[(size_t)i * ldOut + col + c] = v;
                    }
                }
            } else {
#pragma unroll
                for (int c = 0; c < 4; ++c) {
                    float v = acc[r][c];
                    if constexpr (BIAS) v += bias[col + c];
                    if constexpr (RELU) v = fmaxf(v, 0.f);
                    const size_t o = (size_t)i * 512 + col + c;
                    joint[o] += qrepr[o] * v;        // joint += q_repr * v_repr
                }
            }
        }
    }
}

// ---------------- big MFMA GEMM + fused score epilogue ----------------
// hdn_pre = img_org @ Wa_top  (M=150528, K=512, N=512), bf16 MFMA.
// epilogue: s0[row] += sum_col relu(hdn_pre + qproj[br][col]) * Wl[col]
__global__ __launch_bounds__(256) void k_gemm_big(
    const float* __restrict__ A,     // img_org flat [150528][512] f32
    const u16* __restrict__ Bt,      // WaT bf16 [512][512] (row n, col k)
    const float* __restrict__ qproj, // [768][512], ba folded in
    const float* __restrict__ Wl,    // [512]
    float* __restrict__ s0) {        // [150528], zero-initialized
    __shared__ u16 As[128 * 32];
    __shared__ u16 Bs[128 * 32];
    const int t = threadIdx.x;
    const int m0 = blockIdx.x * 128;
    const int n0 = blockIdx.y * 128;
    const int l = t & 63, w = t >> 6;
    const int wm = w >> 1, wn = w & 1;
    const int lg = l >> 4, ln = l & 15;

    f32x4 acc[4][4];
#pragma unroll
    for (int i = 0; i < 4; ++i)
#pragma unroll
        for (int j = 0; j < 4; ++j) acc[i][j] = (f32x4)0.f;

    const int srow = t >> 1;                 // staging: 2 threads/row
    const int shalf = t & 1;                 // 16-element k-half
    const int sw = (srow ^ (srow >> 2)) & 3; // XOR swizzle -> 2-way (free) banks

    for (int kt = 0; kt < 16; ++kt) {
        const float* ap = A + (size_t)(m0 + srow) * 512 + kt * 32 + shalf * 16;
        float4 f0 = ((const float4*)ap)[0];
        float4 f1 = ((const float4*)ap)[1];
        float4 f2 = ((const float4*)ap)[2];
        float4 f3 = ((const float4*)ap)[3];
        const u16* bp = Bt + (size_t)(n0 + srow) * 512 + kt * 32 + shalf * 16;
        uint4 b0 = ((const uint4*)bp)[0];
        uint4 b1 = ((const uint4*)bp)[1];

        union Pk { u16 u[8]; uint4 v; };
        Pk pa0, pa1;
        pa0.u[0] = f2bf(f0.x); pa0.u[1] = f2bf(f0.y); pa0.u[2] = f2bf(f0.z); pa0.u[3] = f2bf(f0.w);
        pa0.u[4] = f2bf(f1.x); pa0.u[5] = f2bf(f1.y); pa0.u[6] = f2bf(f1.z); pa0.u[7] = f2bf(f1.w);
        pa1.u[0] = f2bf(f2.x); pa1.u[1] = f2bf(f2.y); pa1.u[2] = f2bf(f2.z); pa1.u[3] = f2bf(f2.w);
        pa1.u[4] = f2bf(f3.x); pa1.u[5] = f2bf(f3.y); pa1.u[6] = f2bf(f3.z); pa1.u[7] = f2bf(f3.w);

        __syncthreads();  // previous iter's frag reads done
        const int g0 = shalf * 2;
        *(uint4*)&As[srow * 32 + ((g0 ^ sw)) * 8] = pa0.v;
        *(uint4*)&As[srow * 32 + (((g0 + 1) ^ sw)) * 8] = pa1.v;
        *(uint4*)&Bs[srow * 32 + ((g0 ^ sw)) * 8] = b0;
        *(uint4*)&Bs[srow * 32 + (((g0 + 1) ^ sw)) * 8] = b1;
        __syncthreads();

        bf16x8 af[4], bfr[4];
#pragma unroll
        for (int mf = 0; mf < 4; ++mf) {
            const int ar = wm * 64 + mf * 16 + ln;
            const int s = (ar ^ (ar >> 2)) & 3;
            af[mf] = *(const bf16x8*)&As[ar * 32 + ((lg ^ s)) * 8];
        }
#pragma unroll
        for (int nf = 0; nf < 4; ++nf) {
            const int br2 = wn * 64 + nf * 16 + ln;
            const int s = (br2 ^ (br2 >> 2)) & 3;
            bfr[nf] = *(const bf16x8*)&Bs[br2 * 32 + ((lg ^ s)) * 8];
        }
#pragma unroll
        for (int mf = 0; mf < 4; ++mf)
#pragma unroll
            for (int nf = 0; nf < 4; ++nf)
                acc[mf][nf] = __builtin_amdgcn_mfma_f32_16x16x32_bf16(
                    af[mf], bfr[nf], acc[mf][nf], 0, 0, 0);
    }

    // fused score epilogue. C/D layout: col = lane&15, row = (lane>>4)*4 + reg.
#pragma unroll
    for (int mf = 0; mf < 4; ++mf) {
#pragma unroll
        for (int j = 0; j < 4; ++j) {
            const int rloc = wm * 64 + mf * 16 + lg * 4 + j;
            const int grow = m0 + rloc;
            const int brow = grow / 196;
            float p = 0.f;
#pragma unroll
            for (int nf = 0; nf < 4; ++nf) {
                const int c = n0 + wn * 64 + nf * 16 + ln;
                float v = acc[mf][nf][j] + qproj[(size_t)brow * 512 + c];
                v = fmaxf(v, 0.f);
                p += v * Wl[c];
            }
            for (int o = 1; o < 16; o <<= 1) p += __shfl_xor(p, o, 16);
            if (ln == 0) atomicAdd(&s0[grow], p);
        }
    }
}

// ---------------- one-time softmax partials over 196 image regions ----------------
__global__ __launch_bounds__(256) void k_p0(const float* __restrict__ img,
                                            const float* __restrict__ s0,
                                            float* __restrict__ P0,
                                            float* __restrict__ Z0) {
    const int br = blockIdx.x, t = threadIdx.x;
    __shared__ float ws[196];
    if (t < 196) ws[t] = expf(s0[(size_t)br * 196 + t]);
    __syncthreads();
    if (t == 0) {
        float z = 0.f;
        for (int n = 0; n < 196; ++n) z += ws[n];
        Z0[br] = z;
    }
    const int h0 = t * 2;
    float a0 = 0.f, a1 = 0.f;
    const float* base = img + (size_t)br * 196 * 512 + h0;
    for (int n = 0; n < 196; ++n) {
        const float2 v = *(const float2*)(base + (size_t)n * 512);
        const float wv = ws[n];
        a0 += wv * v.x; a1 += wv * v.y;
    }
    P0[(size_t)br * 512 + h0] = a0;
    P0[(size_t)br * 512 + h0 + 1] = a1;
}

// ---------------- per-iteration: 5 LOO scores + v_emb ----------------
__global__ __launch_bounds__(256) void k_scores(
    const float* __restrict__ lproj, const float* __restrict__ qproj,
    const float* __restrict__ Wl, const float* __restrict__ joint,
    const float* __restrict__ P0, const float* __restrict__ Z0,
    float* __restrict__ vemb) {
    const int br = blockIdx.x, t = threadIdx.x;
    const int b = br / 6, r = br - b * 6;
    int src[5];
#pragma unroll
    for (int j = 0; j < 5; ++j) src[j] = b * 6 + j + (j >= r ? 1 : 0);

    float pj[5] = {0.f, 0.f, 0.f, 0.f, 0.f};
    for (int h = t; h < 512; h += 256) {
        const float qp = qproj[(size_t)br * 512 + h];
        const float wl = Wl[h];
#pragma unroll
        for (int j = 0; j < 5; ++j) {
            const float v = lproj[(size_t)src[j] * 512 + h] + qp;
            pj[j] += fmaxf(v, 0.f) * wl;
        }
    }
#pragma unroll
    for (int j = 0; j < 5; ++j)
        for (int o = 1; o < 64; o <<= 1) pj[j] += __shfl_xor(pj[j], o, 64);

    __shared__ float wr[4][5];
    __shared__ float wsh[5];
    __shared__ float invZ;
    const int lane = t & 63, wid = t >> 6;
    if (lane == 0)
#pragma unroll
        for (int j = 0; j < 5; ++j) wr[wid][j] = pj[j];
    __syncthreads();
    if (t == 0) {
        float Z = Z0[br];
#pragma unroll
        for (int j = 0; j < 5; ++j) {
            const float s = wr[0][j] + wr[1][j] + wr[2][j] + wr[3][j];
            const float e = expf(s);
            wsh[j] = e; Z += e;
        }
        invZ = 1.f / Z;
    }
    __syncthreads();
    for (int h = t; h < 512; h += 256) {
        float a = P0[(size_t)br * 512 + h];
#pragma unroll
        for (int j = 0; j < 5; ++j) a += wsh[j] * joint[(size_t)src[j] * 512 + h];
        vemb[(size_t)br * 512 + h] = a * invZ;
    }
}

// ---------------- launch ----------------

extern "C" void kernel_launch(void* const* d_in, const int* in_sizes, int n_in,
                              void* d_out, int out_size, void* d_ws, size_t ws_size,
                              hipStream_t stream) {
    (void)in_sizes; (void)n_in; (void)out_size; (void)ws_size;
    const float* img = (const float*)d_in[0];
    const float* q   = (const float*)d_in[1];
    const float* Wq  = (const float*)d_in[2];
    const float* bq  = (const float*)d_in[3];
    const float* Wa  = (const float*)d_in[4];
    const float* ba  = (const float*)d_in[5];
    const float* Wl  = (const float*)d_in[6];
    // d_in[7] = bl: softmax shift-invariant, unused
    const float* Wqn = (const float*)d_in[8];
    const float* bqn = (const float*)d_in[9];
    const float* Wvn = (const float*)d_in[10];
    const float* bvn = (const float*)d_in[11];
    const float* Wc1 = (const float*)d_in[12];
    const float* bc1 = (const float*)d_in[13];
    const float* Wc2 = (const float*)d_in[14];
    const float* bc2 = (const float*)d_in[15];

    float* wsf   = (float*)d_ws;
    float* q_emb = wsf + OFF_QEMB;
    float* q_rep = wsf + OFF_QREPR;
    float* qproj = wsf + OFF_QPROJ;
    float* joint = wsf + OFF_JOINT;
    float* lproj = wsf + OFF_LPROJ;
    float* vemb  = wsf + OFF_VEMB;
    float* P0    = wsf + OFF_P0;
    float* hid   = wsf + OFF_HID;
    float* s0    = wsf + OFF_S0;
    float* Z0    = wsf + OFF_Z0;
    float* Wc2p  = wsf + OFF_WC2P;
    u16*   WaT   = (u16*)(wsf + OFF_WAT);

    float* logits   = (float*)d_out;
    float* jointOut = logits + (size_t)BR_ * V_;

    k_zero<<<(MBIG + BR_ * H_) / 256, 256, 0, stream>>>(s0, joint);
    k_castWaT<<<512 * 512 / 256, 256, 0, stream>>>(Wa, WaT);
    k_padWc2<<<1024 * VP / 256, 256, 0, stream>>>(Wc2, Wc2p);

    // q_emb = relu(q@Wq + bq)
    k_rowgemm<600, true, true, 0><<<dim3(96, 1), 256, 0, stream>>>(
        q, Wq, 512, bq, q_emb, 512, 512, nullptr, nullptr);
    // q_repr = relu(q_emb@Wqn + bqn)
    k_rowgemm<512, true, true, 0><<<dim3(96, 1), 256, 0, stream>>>(
        q_emb, Wqn, 512, bqn, q_rep, 512, 512, nullptr, nullptr);
    // qproj = q_emb@Wa_bot + ba (no relu)
    k_rowgemm<512, false, true, 0><<<dim3(96, 1), 256, 0, stream>>>(
        q_emb, Wa + (size_t)512 * 512, 512, ba, qproj, 512, 512, nullptr, nullptr);
    // loop-invariant region scores s0 (atomic partial sums over 4 col-blocks)
    k_gemm_big<<<dim3(MBIG / 128, 4), 256, 0, stream>>>(img, WaT, qproj, Wl, s0);
    // P0, Z0
    k_p0<<<BR_, 256, 0, stream>>>(img, s0, P0, Z0);

    for (int it = 0; it < 3; ++it) {
        // lproj = joint @ Wa_top
        k_rowgemm<512, false, false, 0><<<dim3(96, 1), 256, 0, stream>>>(
            joint, Wa, 512, nullptr, lproj, 512, 512, nullptr, nullptr);
        k_scores<<<BR_, 256, 0, stream>>>(lproj, qproj, Wl, joint, P0, Z0, vemb);
        // v_repr = relu(vemb@Wvn + bvn); joint += q_repr * v_repr
        k_rowgemm<512, true, true, 1><<<dim3(96, 1), 256, 0, stream>>>(
            vemb, Wvn, 512, bvn, nullptr, 512, 512, q_rep, joint);
    }

    // classifier
    k_rowgemm<512, true, true, 0><<<dim3(96, 2), 256, 0, stream>>>(
        joint, Wc1, 1024, bc1, hid, 1024, 1024, nullptr, nullptr);
    k_rowgemm<1024, false, true, 0><<<dim3(96, 4), 256, 0, stream>>>(
        hid, Wc2p, VP, bc2, logits, V_, V_, nullptr, nullptr);
    // second output: joint
    k_copy4<<<BR_ * H_ / 1024, 256, 0, stream>>>((const float4*)joint,
                                                 (float4*)jointOut);
}